// Round 5
// baseline (151.124 us; speedup 1.0000x reference)
//
#include <hip/hip_runtime.h>
#include <hip/hip_bf16.h>

typedef __attribute__((ext_vector_type(4))) short bf16x4;   // 4 bf16 = 2 VGPR
typedef __attribute__((ext_vector_type(4))) float f32x4;
typedef __attribute__((ext_vector_type(4))) int i32x4;

#define LOG2E 1.4426950408889634f

static __device__ inline f32x4 mfma16(bf16x4 a, bf16x4 b, f32x4 c) {
  return __builtin_amdgcn_mfma_f32_16x16x16bf16_1k(a, b, c, 0, 0, 0);
}
static __device__ inline ushort f2bfu(float f) {
  __hip_bfloat16 h = __float2bfloat16(f);
  return *(ushort*)&h;
}

// ---------------------------------------------------------------------------
// Fused QKV projection: x[8192x128] f32 -> Qs, Ks (row-major bf16, Q scaled
// by 0.25*log2e), Vt (transposed bf16: Vt[(b*8+h)*16+d][n]).
// grid 1024 x 256; each wave = one 16x16 output tile for all three mats.
// ---------------------------------------------------------------------------
__global__ __launch_bounds__(256) void gemm_qkv(
    const float* __restrict__ x,
    const float* __restrict__ Wq, const float* __restrict__ bq,
    const float* __restrict__ Wk, const float* __restrict__ bk,
    const float* __restrict__ Wv, const float* __restrict__ bv,
    ushort* __restrict__ Qs, ushort* __restrict__ Ks, ushort* __restrict__ Vt) {
  const int tid = threadIdx.x;
  const int l = tid & 63, w = tid >> 6;
  const int lm = l & 15, g = l >> 4;
  const int tile = blockIdx.x * 4 + w;      // 0..4095
  const int mt = tile >> 3, nt = tile & 7;  // 512 x 8 tiles
  const int row = mt * 16 + lm;
  const int col = nt * 16 + lm;

  f32x4 accq = {0.f,0.f,0.f,0.f}, acck = {0.f,0.f,0.f,0.f}, accv = {0.f,0.f,0.f,0.f};
#pragma unroll
  for (int ks = 0; ks < 8; ++ks) {
    f32x4 xa = *(const f32x4*)(x + (size_t)row * 128 + ks * 16 + g * 4);
    bf16x4 a;
    a[0] = (short)f2bfu(xa[0]); a[1] = (short)f2bfu(xa[1]);
    a[2] = (short)f2bfu(xa[2]); a[3] = (short)f2bfu(xa[3]);
    const size_t wo = (size_t)(ks * 16 + g * 4) * 128 + col;
    bf16x4 bqf, bkf, bvf;
#pragma unroll
    for (int j = 0; j < 4; ++j) {
      bqf[j] = (short)f2bfu(Wq[wo + 128 * j]);
      bkf[j] = (short)f2bfu(Wk[wo + 128 * j]);
      bvf[j] = (short)f2bfu(Wv[wo + 128 * j]);
    }
    accq = mfma16(a, bqf, accq);
    acck = mfma16(a, bkf, acck);
    accv = mfma16(a, bvf, accv);
  }
  const float bqv = bq[col], bkv = bk[col], bvv = bv[col];
  const float QSCALE = 0.25f * LOG2E;
#pragma unroll
  for (int r = 0; r < 4; ++r) {
    const size_t orow = (size_t)mt * 16 + g * 4 + r;
    Qs[orow * 128 + col] = f2bfu((accq[r] + bqv) * QSCALE);
    Ks[orow * 128 + col] = f2bfu(acck[r] + bkv);
  }
  // Vt: V[n][h*16+d] -> Vt[((b*8+h)*16+d)*1024 + n], 4 consecutive n per lane
  {
    const int nbase = mt * 16 + g * 4;
    const int vb = (mt * 16) >> 10;
    const int nloc = nbase & 1023;
    bf16x4 vv;
    vv[0] = (short)f2bfu(accv[0] + bvv); vv[1] = (short)f2bfu(accv[1] + bvv);
    vv[2] = (short)f2bfu(accv[2] + bvv); vv[3] = (short)f2bfu(accv[3] + bvv);
    *(bf16x4*)(Vt + (((size_t)vb * 8 + nt) * 16 + lm) * 1024 + nloc) = vv;
  }
}

// ---------------------------------------------------------------------------
// Fused graph attention, LDS-free / barrier-free. One wave = one (b, m-tile
// of 16, head). 64 columns per iteration, 16 iterations, log2-domain online
// softmax. adj/edge tiles read directly from L2 (b128 per lane).
// grid 1024 x 256 (4 waves/block = heads half*4 + w).
// ---------------------------------------------------------------------------
__global__ __launch_bounds__(256) void attn_kernel(
    const ushort* __restrict__ Qs, const ushort* __restrict__ Ks,
    const ushort* __restrict__ Vt, const int* __restrict__ adj,
    const float* __restrict__ edge, const float* __restrict__ We,
    ushort* __restrict__ AO) {
  const int tid = threadIdx.x;
  const int l = tid & 63, w = tid >> 6;
  const int lm = l & 15, g = l >> 4;
  const int bid = blockIdx.x;
  const int b = bid >> 7;
  const int m0 = ((bid >> 1) & 63) * 16;
  const int h = (bid & 1) * 4 + w;

  const float Weh = We[h] * LOG2E;
  // B-frag of S^T = K.Q^T : lane holds Q[m0+lm][k=4g+j]  (log2e/4 pre-folded)
  const bf16x4 qf = *(const bf16x4*)(Qs + ((size_t)b * 1024 + m0 + lm) * 128 + h * 16 + g * 4);

  const int*    ap = adj  + (size_t)b * 1048576 + (size_t)(m0 + lm) * 1024 + g * 4;
  const float*  ep = edge + (size_t)b * 1048576 + (size_t)(m0 + lm) * 1024 + g * 4;
  const ushort* kp = Ks + ((size_t)b * 1024 + lm) * 128 + h * 16 + g * 4;
  const ushort* vp = Vt + (((size_t)b * 8 + h) * 16 + lm) * 1024 + g * 4;

  float mmax = -1e30f, lsum = 0.f;
  f32x4 oacc = {0.f, 0.f, 0.f, 0.f};

  for (int ct = 0; ct < 16; ++ct) {
    const int n0 = ct * 64;
    i32x4 a4[4]; f32x4 e4[4]; bf16x4 kf[4], vf[4];
#pragma unroll
    for (int t = 0; t < 4; ++t) {
      a4[t] = *(const i32x4*)(ap + n0 + t * 16);
      e4[t] = *(const f32x4*)(ep + n0 + t * 16);
      kf[t] = *(const bf16x4*)(kp + (size_t)(n0 + t * 16) * 128);  // K[n0+16t+lm][4g+j]
      vf[t] = *(const bf16x4*)(vp + n0 + t * 16);                  // V^T[lm][n0+16t+4g+j]
    }
    // S^T sub-tiles: lane l, reg j -> (n = n0+16t+4g+j, m = m0+lm)
    f32x4 st[4];
#pragma unroll
    for (int t = 0; t < 4; ++t) {
      f32x4 z = {0.f, 0.f, 0.f, 0.f};
      st[t] = mfma16(kf[t], qf, z);
    }
    float s[16];
#pragma unroll
    for (int t = 0; t < 4; ++t)
#pragma unroll
      for (int j = 0; j < 4; ++j)
        s[t * 4 + j] = (a4[t][j] == 0) ? -INFINITY : fmaf(e4[t][j], Weh, st[t][j]);

    float tmax = s[0];
#pragma unroll
    for (int i = 1; i < 16; ++i) tmax = fmaxf(tmax, s[i]);
    tmax = fmaxf(tmax, __shfl_xor(tmax, 16, 64));
    tmax = fmaxf(tmax, __shfl_xor(tmax, 32, 64));

    const float mnew = fmaxf(mmax, tmax);           // tmax=-inf ok
    const float alpha = __builtin_amdgcn_exp2f(mmax - mnew);
    float p[16], psum = 0.f;
#pragma unroll
    for (int i = 0; i < 16; ++i) {
      p[i] = __builtin_amdgcn_exp2f(s[i] - mnew);   // exp2(-inf)=0 for masked
      psum += p[i];
    }
    psum += __shfl_xor(psum, 16, 64);
    psum += __shfl_xor(psum, 32, 64);
    lsum = lsum * alpha + psum;
    mmax = mnew;
    oacc[0] *= alpha; oacc[1] *= alpha; oacc[2] *= alpha; oacc[3] *= alpha;

    // P^T (S^T C/D layout) == B-frag of PV mfma; O^T[d=4g+r][m=lm]
#pragma unroll
    for (int t = 0; t < 4; ++t) {
      bf16x4 pf;
      pf[0] = (short)f2bfu(p[t * 4 + 0]); pf[1] = (short)f2bfu(p[t * 4 + 1]);
      pf[2] = (short)f2bfu(p[t * 4 + 2]); pf[3] = (short)f2bfu(p[t * 4 + 3]);
      oacc = mfma16(vf[t], pf, oacc);
    }
  }

  const float inv = 1.0f / lsum;
  bf16x4 ov;
  ov[0] = (short)f2bfu(oacc[0] * inv);
  ov[1] = (short)f2bfu(oacc[1] * inv);
  ov[2] = (short)f2bfu(oacc[2] * inv);
  ov[3] = (short)f2bfu(oacc[3] * inv);
  *(bf16x4*)(AO + ((size_t)b * 1024 + m0 + lm) * 128 + h * 16 + g * 4) = ov;
}

// ---------------------------------------------------------------------------
// Output projection: AO (bf16) @ Wo + bo -> f32 out.
// ---------------------------------------------------------------------------
__global__ __launch_bounds__(256) void gemm_out(
    const ushort* __restrict__ A, const float* __restrict__ W,
    const float* __restrict__ bias, float* __restrict__ C) {
  const int tid = threadIdx.x;
  const int l = tid & 63, w = tid >> 6;
  const int lm = l & 15, g = l >> 4;
  const int tile = blockIdx.x * 4 + w;
  const int mt = tile >> 3, nt = tile & 7;
  const int row = mt * 16 + lm;
  const int col = nt * 16 + lm;

  f32x4 acc = {0.f, 0.f, 0.f, 0.f};
#pragma unroll
  for (int ks = 0; ks < 8; ++ks) {
    bf16x4 a = *(const bf16x4*)(A + (size_t)row * 128 + ks * 16 + g * 4);
    const float* wp = W + (size_t)(ks * 16 + g * 4) * 128 + col;
    bf16x4 bf;
    bf[0] = (short)f2bfu(wp[0]);   bf[1] = (short)f2bfu(wp[128]);
    bf[2] = (short)f2bfu(wp[256]); bf[3] = (short)f2bfu(wp[384]);
    acc = mfma16(a, bf, acc);
  }
  const float bv = bias[col];
#pragma unroll
  for (int r = 0; r < 4; ++r)
    C[(size_t)(mt * 16 + g * 4 + r) * 128 + col] = acc[r] + bv;
}

extern "C" void kernel_launch(void* const* d_in, const int* in_sizes, int n_in,
                              void* d_out, int out_size, void* d_ws, size_t ws_size,
                              hipStream_t stream) {
  const float* x   = (const float*)d_in[0];
  const int*   adj = (const int*)d_in[1];
  const float* ew  = (const float*)d_in[2];
  const float* Wq  = (const float*)d_in[3];
  const float* bq  = (const float*)d_in[4];
  const float* Wk  = (const float*)d_in[5];
  const float* bk  = (const float*)d_in[6];
  const float* Wv  = (const float*)d_in[7];
  const float* bv  = (const float*)d_in[8];
  const float* Wo  = (const float*)d_in[9];
  const float* bo  = (const float*)d_in[10];
  const float* We  = (const float*)d_in[11];
  // const float* be = (const float*)d_in[12];  // exact: softmax(x+c)=softmax(x)

  const size_t MN = (size_t)8 * 1024 * 128;  // 1M elements
  ushort* Qs = (ushort*)d_ws;
  ushort* Ks = Qs + MN;
  ushort* Vt = Ks + MN;
  ushort* AO = Vt + MN;

  gemm_qkv<<<1024, 256, 0, stream>>>(x, Wq, bq, Wk, bk, Wv, bv, Qs, Ks, Vt);
  attn_kernel<<<1024, 256, 0, stream>>>(Qs, Ks, Vt, adj, ew, We, AO);
  gemm_out<<<1024, 256, 0, stream>>>(AO, Wo, bo, (float*)d_out);
}

// Round 6
// 100.522 us; speedup vs baseline: 1.5034x; 1.5034x over previous
//
#include <hip/hip_runtime.h>
#include <hip/hip_bf16.h>

typedef __attribute__((ext_vector_type(4))) short bf16x4;   // 4 bf16 = 2 VGPR
typedef __attribute__((ext_vector_type(4))) float f32x4;
typedef __attribute__((ext_vector_type(4))) int i32x4;

#define LOG2E 1.4426950408889634f
#define SMAX 8.0f   // fixed softmax shift (log2 domain); exact after normalization

static __device__ inline f32x4 mfma16(bf16x4 a, bf16x4 b, f32x4 c) {
  return __builtin_amdgcn_mfma_f32_16x16x16bf16_1k(a, b, c, 0, 0, 0);
}
static __device__ inline ushort f2bfu(float f) {
  __hip_bfloat16 h = __float2bfloat16(f);
  return *(ushort*)&h;
}

// ---------------------------------------------------------------------------
// Input projections: C = (x @ W + b) * alpha. x f32 [8192x128], C bf16.
// VT=false: row-major C[m][col]. VT=true: block-transposed V^T layout
//   Vt[((b*8+h)*16 + (n>>6))*1024 + d*64 + (n&63)]   (h=nt, d=lm)
// grid 1024 x 256; one 16x16 tile per wave.
// ---------------------------------------------------------------------------
template <bool VT>
__global__ __launch_bounds__(256) void gemm_in(
    const float* __restrict__ A, const float* __restrict__ W,
    const float* __restrict__ bias, ushort* __restrict__ C, float alpha) {
  const int tid = threadIdx.x;
  const int l = tid & 63, w = tid >> 6;
  const int lm = l & 15, g = l >> 4;
  const int tile = blockIdx.x * 4 + w;      // 0..4095
  const int mt = tile >> 3, nt = tile & 7;  // 512 x 8 tiles
  const int row = mt * 16 + lm;
  const int col = nt * 16 + lm;

  f32x4 acc = {0.f, 0.f, 0.f, 0.f};
#pragma unroll
  for (int ks = 0; ks < 8; ++ks) {
    f32x4 av = *(const f32x4*)(A + (size_t)row * 128 + ks * 16 + g * 4);
    bf16x4 a;
    a[0] = (short)f2bfu(av[0]); a[1] = (short)f2bfu(av[1]);
    a[2] = (short)f2bfu(av[2]); a[3] = (short)f2bfu(av[3]);
    const float* wp = W + (size_t)(ks * 16 + g * 4) * 128 + col;
    bf16x4 b;
    b[0] = (short)f2bfu(wp[0]);   b[1] = (short)f2bfu(wp[128]);
    b[2] = (short)f2bfu(wp[256]); b[3] = (short)f2bfu(wp[384]);
    acc = mfma16(a, b, acc);
  }
  const float bv = bias[col];
  if constexpr (VT) {
    // lane holds V[m = mt*16+4g+r][h*16+d], h=nt, d=lm
    const int mb = mt * 16;
    const size_t addr = ((size_t)((mb >> 10) * 8 + nt) * 16 + ((mb & 1023) >> 6)) * 1024
                        + (size_t)lm * 64 + (mb & 63) + g * 4;
    bf16x4 vv;
    vv[0] = (short)f2bfu((acc[0] + bv) * alpha);
    vv[1] = (short)f2bfu((acc[1] + bv) * alpha);
    vv[2] = (short)f2bfu((acc[2] + bv) * alpha);
    vv[3] = (short)f2bfu((acc[3] + bv) * alpha);
    *(bf16x4*)(C + addr) = vv;
  } else {
#pragma unroll
    for (int r = 0; r < 4; ++r)
      C[(size_t)(mt * 16 + g * 4 + r) * 128 + col] = f2bfu((acc[r] + bv) * alpha);
  }
}

// ---------------------------------------------------------------------------
// Fused graph attention. One WG = (b, 16-row m-tile); 8 waves = 8 heads.
// 16 iterations x 64 columns. adj/edge staged in double-buffered LDS by all
// 512 threads; fixed-shift log2-domain softmax (no online max, no per-iter
// cross-lane ops); V consumed from block-transposed Vt (b64 loads).
// ---------------------------------------------------------------------------
#define STI 68  // LDS row stride (elements); 68*4=272B, 16B-aligned rows

__global__ __launch_bounds__(512) void attn_kernel(
    const ushort* __restrict__ Qs, const ushort* __restrict__ Ks,
    const ushort* __restrict__ Vt, const int* __restrict__ adj,
    const float* __restrict__ edge, const float* __restrict__ We,
    ushort* __restrict__ AO) {
  __shared__ int   adj_lds[2][16 * STI];
  __shared__ float edge_lds[2][16 * STI];

  const int tid = threadIdx.x;
  const int l = tid & 63, h = tid >> 6;
  const int lm = l & 15, g = l >> 4;
  const int b = blockIdx.x >> 6;
  const int m0 = (blockIdx.x & 63) * 16;

  const float Weh = We[h] * LOG2E;
  // B-frag of S^T = K.Q^T : lane holds Q[m0+lm][k=4g+j] (0.25*log2e folded)
  const bf16x4 qf = *(const bf16x4*)(Qs + ((size_t)b * 1024 + m0 + lm) * 128 + h * 16 + g * 4);

  const ushort* kp = Ks + ((size_t)b * 1024 + lm) * 128 + h * 16 + g * 4;
  const ushort* vp = Vt + ((size_t)b * 8 + h) * 16384 + (size_t)lm * 64 + g * 4;

  // staging roles: tid<256 -> adj, tid>=256 -> edge; one b128 each per iter
  const int sr = (tid & 255) >> 4;   // row 0..15
  const int sc = (tid & 15) * 4;     // col group
  const bool s_adj = (tid < 256);
  const int*   agp = adj  + (size_t)b * 1048576 + (size_t)(m0 + sr) * 1024 + sc;
  const float* egp = edge + (size_t)b * 1048576 + (size_t)(m0 + sr) * 1024 + sc;

  // prologue: stage tile 0
  if (s_adj) *(i32x4*)&adj_lds[0][sr * STI + sc]  = *(const i32x4*)agp;
  else       *(f32x4*)&edge_lds[0][sr * STI + sc] = *(const f32x4*)egp;

  float lsum = 0.f;
  f32x4 oacc = {0.f, 0.f, 0.f, 0.f};
  const f32x4 cinit = {-SMAX, -SMAX, -SMAX, -SMAX};

  for (int ct = 0; ct < 16; ++ct) {
    __syncthreads();  // buf[ct&1] staged; prior reads of buf[(ct+1)&1] done
    const int buf = ct & 1;
    const int n0 = ct * 64;
    const bool pfch = (ct < 15);

    i32x4 pa; f32x4 pe;
    if (pfch) {
      if (s_adj) pa = *(const i32x4*)(agp + n0 + 64);
      else       pe = *(const f32x4*)(egp + n0 + 64);
    }

    bf16x4 kf[4], vf[4];
#pragma unroll
    for (int t = 0; t < 4; ++t) {
      kf[t] = *(const bf16x4*)(kp + (size_t)(n0 + t * 16) * 128);  // K[n][4g+j]
      vf[t] = *(const bf16x4*)(vp + (size_t)ct * 1024 + t * 16);   // V^T[lm][..]
    }
    // S^T sub-tiles (pre-shifted by -SMAX): lane l, reg j -> (n=n0+16t+4g+j, m=m0+lm)
    f32x4 st[4];
#pragma unroll
    for (int t = 0; t < 4; ++t) st[t] = mfma16(kf[t], qf, cinit);

#pragma unroll
    for (int t = 0; t < 4; ++t) {
      const i32x4 a4 = *(const i32x4*)&adj_lds[buf][lm * STI + t * 16 + g * 4];
      const f32x4 e4 = *(const f32x4*)&edge_lds[buf][lm * STI + t * 16 + g * 4];
      bf16x4 pf4;
#pragma unroll
      for (int j = 0; j < 4; ++j) {
        float p = __builtin_amdgcn_exp2f(fmaf(e4[j], Weh, st[t][j]));
        p = (a4[j] == 0) ? 0.f : p;
        lsum += p;
        pf4[j] = (short)f2bfu(p);
      }
      // P^T (S^T C/D layout) == B-frag of PV; O^T[d=4g+r][m=lm]
      oacc = mfma16(vf[t], pf4, oacc);
    }

    if (pfch) {
      if (s_adj) *(i32x4*)&adj_lds[buf ^ 1][sr * STI + sc]  = pa;
      else       *(f32x4*)&edge_lds[buf ^ 1][sr * STI + sc] = pe;
    }
  }

  // full row-sum: lanes {lm, lm+16, lm+32, lm+48} hold partials of row lm
  lsum += __shfl_xor(lsum, 16, 64);
  lsum += __shfl_xor(lsum, 32, 64);
  const float inv = 1.0f / lsum;
  bf16x4 ov;
  ov[0] = (short)f2bfu(oacc[0] * inv);
  ov[1] = (short)f2bfu(oacc[1] * inv);
  ov[2] = (short)f2bfu(oacc[2] * inv);
  ov[3] = (short)f2bfu(oacc[3] * inv);
  *(bf16x4*)(AO + ((size_t)b * 1024 + m0 + lm) * 128 + h * 16 + g * 4) = ov;
}

// ---------------------------------------------------------------------------
// Output projection: AO (bf16) @ Wo + bo -> f32 out.
// ---------------------------------------------------------------------------
__global__ __launch_bounds__(256) void gemm_out(
    const ushort* __restrict__ A, const float* __restrict__ W,
    const float* __restrict__ bias, float* __restrict__ C) {
  const int tid = threadIdx.x;
  const int l = tid & 63, w = tid >> 6;
  const int lm = l & 15, g = l >> 4;
  const int tile = blockIdx.x * 4 + w;
  const int mt = tile >> 3, nt = tile & 7;
  const int row = mt * 16 + lm;
  const int col = nt * 16 + lm;

  f32x4 acc = {0.f, 0.f, 0.f, 0.f};
#pragma unroll
  for (int ks = 0; ks < 8; ++ks) {
    bf16x4 a = *(const bf16x4*)(A + (size_t)row * 128 + ks * 16 + g * 4);
    const float* wp = W + (size_t)(ks * 16 + g * 4) * 128 + col;
    bf16x4 bf;
    bf[0] = (short)f2bfu(wp[0]);   bf[1] = (short)f2bfu(wp[128]);
    bf[2] = (short)f2bfu(wp[256]); bf[3] = (short)f2bfu(wp[384]);
    acc = mfma16(a, bf, acc);
  }
  const float bv = bias[col];
#pragma unroll
  for (int r = 0; r < 4; ++r)
    C[(size_t)(mt * 16 + g * 4 + r) * 128 + col] = acc[r] + bv;
}

extern "C" void kernel_launch(void* const* d_in, const int* in_sizes, int n_in,
                              void* d_out, int out_size, void* d_ws, size_t ws_size,
                              hipStream_t stream) {
  const float* x   = (const float*)d_in[0];
  const int*   adj = (const int*)d_in[1];
  const float* ew  = (const float*)d_in[2];
  const float* Wq  = (const float*)d_in[3];
  const float* bq  = (const float*)d_in[4];
  const float* Wk  = (const float*)d_in[5];
  const float* bk  = (const float*)d_in[6];
  const float* Wv  = (const float*)d_in[7];
  const float* bv  = (const float*)d_in[8];
  const float* Wo  = (const float*)d_in[9];
  const float* bo  = (const float*)d_in[10];
  const float* We  = (const float*)d_in[11];
  // be (d_in[12]) dropped: softmax(x + c) == softmax(x)

  const size_t MN = (size_t)8 * 1024 * 128;  // 1M elements
  ushort* Qs = (ushort*)d_ws;
  ushort* Ks = Qs + MN;
  ushort* Vt = Ks + MN;
  ushort* AO = Vt + MN;

  gemm_in<false><<<1024, 256, 0, stream>>>(x, Wq, bq, Qs, 0.25f * LOG2E);
  gemm_in<false><<<1024, 256, 0, stream>>>(x, Wk, bk, Ks, 1.0f);
  gemm_in<true ><<<1024, 256, 0, stream>>>(x, Wv, bv, Vt, 1.0f);
  attn_kernel<<<512, 512, 0, stream>>>(Qs, Ks, Vt, adj, ew, We, AO);
  gemm_out<<<1024, 256, 0, stream>>>(AO, Wo, bo, (float*)d_out);
}

// Round 7
// 90.424 us; speedup vs baseline: 1.6713x; 1.1117x over previous
//
#include <hip/hip_runtime.h>
#include <hip/hip_bf16.h>

typedef __attribute__((ext_vector_type(4))) short bf16x4;   // 4 bf16 = 2 VGPR
typedef __attribute__((ext_vector_type(4))) float f32x4;
typedef __attribute__((ext_vector_type(4))) int i32x4;

#define LOG2E 1.4426950408889634f
#define SMAX 8.0f   // fixed softmax shift (log2 domain); exact after normalization

static __device__ inline f32x4 mfma16(bf16x4 a, bf16x4 b, f32x4 c) {
  return __builtin_amdgcn_mfma_f32_16x16x16bf16_1k(a, b, c, 0, 0, 0);
}
static __device__ inline ushort f2bfu(float f) {
  __hip_bfloat16 h = __float2bfloat16(f);
  return *(ushort*)&h;
}

// ---------------------------------------------------------------------------
// Input projections: C = (x @ W + b) * alpha. x f32 [8192x128], C bf16.
// MODE 0: row-major C[m][col]           (Q)
// MODE 1: per-head K^T16: Kt[((b*8+h)*1024 + n)*16 + k]   (h=nt, k=lm)
// MODE 2: block-transposed V^T: Vt[((b*8+h)*16 + (n>>6))*1024 + d*64 + (n&63)]
// grid 1024 x 256; one 16x16 tile per wave.
// ---------------------------------------------------------------------------
template <int MODE>
__global__ __launch_bounds__(256) void gemm_in(
    const float* __restrict__ A, const float* __restrict__ W,
    const float* __restrict__ bias, ushort* __restrict__ C, float alpha) {
  const int tid = threadIdx.x;
  const int l = tid & 63, w = tid >> 6;
  const int lm = l & 15, g = l >> 4;
  const int tile = blockIdx.x * 4 + w;      // 0..4095
  const int mt = tile >> 3, nt = tile & 7;  // 512 x 8 tiles
  const int row = mt * 16 + lm;
  const int col = nt * 16 + lm;

  f32x4 acc = {0.f, 0.f, 0.f, 0.f};
#pragma unroll
  for (int ks = 0; ks < 8; ++ks) {
    f32x4 av = *(const f32x4*)(A + (size_t)row * 128 + ks * 16 + g * 4);
    bf16x4 a;
    a[0] = (short)f2bfu(av[0]); a[1] = (short)f2bfu(av[1]);
    a[2] = (short)f2bfu(av[2]); a[3] = (short)f2bfu(av[3]);
    const float* wp = W + (size_t)(ks * 16 + g * 4) * 128 + col;
    bf16x4 b;
    b[0] = (short)f2bfu(wp[0]);   b[1] = (short)f2bfu(wp[128]);
    b[2] = (short)f2bfu(wp[256]); b[3] = (short)f2bfu(wp[384]);
    acc = mfma16(a, b, acc);
  }
  const float bv = bias[col];
  float v0 = (acc[0] + bv) * alpha, v1 = (acc[1] + bv) * alpha;
  float v2 = (acc[2] + bv) * alpha, v3 = (acc[3] + bv) * alpha;
  const int mb = mt * 16;

  if constexpr (MODE == 0) {
    C[(size_t)(mb + g * 4 + 0) * 128 + col] = f2bfu(v0);
    C[(size_t)(mb + g * 4 + 1) * 128 + col] = f2bfu(v1);
    C[(size_t)(mb + g * 4 + 2) * 128 + col] = f2bfu(v2);
    C[(size_t)(mb + g * 4 + 3) * 128 + col] = f2bfu(v3);
  } else if constexpr (MODE == 1) {
    // n = mb + 4g + r, h = nt, k = lm
    const size_t kb = ((size_t)((mb >> 10) * 8 + nt) * 1024 + ((mb & 1023) + g * 4));
    C[(kb + 0) * 16 + lm] = f2bfu(v0);
    C[(kb + 1) * 16 + lm] = f2bfu(v1);
    C[(kb + 2) * 16 + lm] = f2bfu(v2);
    C[(kb + 3) * 16 + lm] = f2bfu(v3);
  } else {
    // V: n = mb + 4g + r (j contiguous), d = lm, h = nt
    const size_t addr = ((size_t)((mb >> 10) * 8 + nt) * 16 + ((mb & 1023) >> 6)) * 1024
                        + (size_t)lm * 64 + (mb & 63) + g * 4;
    bf16x4 vv;
    vv[0] = (short)f2bfu(v0); vv[1] = (short)f2bfu(v1);
    vv[2] = (short)f2bfu(v2); vv[3] = (short)f2bfu(v3);
    *(bf16x4*)(C + addr) = vv;
  }
}

// ---------------------------------------------------------------------------
// Fused graph attention. One WG = (b, 16-row m-tile); 8 waves = 8 heads.
// 16 iterations x 64 columns, staggered start per WG (commutative softmax).
// adj/edge: triple-buffered LDS, prefetch depth 3 (issue ct+4, write ct+1).
// K/V fragments register-prefetched one iteration ahead.
// Fixed-shift log2-domain softmax; V from block-transposed Vt, K from Kt16.
// ---------------------------------------------------------------------------
#define STI 68  // LDS row stride (ints); bank-spread for 16-row b128 reads

__global__ __launch_bounds__(512) void attn_kernel(
    const ushort* __restrict__ Qs, const ushort* __restrict__ Kt,
    const ushort* __restrict__ Vt, const int* __restrict__ adj,
    const float* __restrict__ edge, const float* __restrict__ We,
    ushort* __restrict__ AO) {
  __shared__ int adj_lds[3][16 * STI];
  __shared__ int edge_lds[3][16 * STI];   // float bits stored as int

  const int tid = threadIdx.x;
  const int l = tid & 63, h = tid >> 6;
  const int lm = l & 15, g = l >> 4;
  const int b = blockIdx.x >> 6;
  const int m0 = (blockIdx.x & 63) * 16;
  const int off = (blockIdx.x * 5) & 15;   // stagger: decorrelate HBM bursts
#define TIDX(t) (((t) + off) & 15)

  const float Weh = We[h] * LOG2E;
  // B-frag of S^T = K.Q^T : lane holds Q[m0+lm][k=4g+j] (0.25*log2e folded)
  const bf16x4 qf = *(const bf16x4*)(Qs + ((size_t)b * 1024 + m0 + lm) * 128 + h * 16 + g * 4);

  const ushort* kbase = Kt + ((size_t)b * 8 + h) * 16384 + (size_t)lm * 16 + g * 4;  // + n0*16
  const ushort* vbase = Vt + ((size_t)b * 8 + h) * 16384 + (size_t)lm * 64 + g * 4;  // + ti*1024

  // staging roles: tid<256 -> adj, else edge; one b128 per tile each
  const int sr = (tid & 255) >> 4, sc = (tid & 15) * 4;
  const bool s_adj = (tid < 256);
  const int* sgp = (s_adj ? adj : (const int*)edge)
                   + (size_t)b * 1048576 + (size_t)(m0 + sr) * 1024 + sc;
  const int lofs = sr * STI + sc;

  i32x4 sreg[3];
  // prologue: tile0 -> buf0; issue tiles 1,2,3 into slots 1,2,0
  {
    i32x4 v = *(const i32x4*)(sgp + TIDX(0) * 64);
    if (s_adj) *(i32x4*)&adj_lds[0][lofs] = v;
    else       *(i32x4*)&edge_lds[0][lofs] = v;
  }
  sreg[1] = *(const i32x4*)(sgp + TIDX(1) * 64);
  sreg[2] = *(const i32x4*)(sgp + TIDX(2) * 64);
  sreg[0] = *(const i32x4*)(sgp + TIDX(3) * 64);

  // K/V fragment prefetch for iter 0
  bf16x4 kf[2][4], vf[2][4];
#pragma unroll
  for (int t = 0; t < 4; ++t) {
    kf[0][t] = *(const bf16x4*)(kbase + (size_t)(TIDX(0) * 64 + t * 16) * 16);
    vf[0][t] = *(const bf16x4*)(vbase + (size_t)TIDX(0) * 1024 + t * 16);
  }

  float lsum = 0.f;
  f32x4 oacc = {0.f, 0.f, 0.f, 0.f};
  const f32x4 cinit = {-SMAX, -SMAX, -SMAX, -SMAX};

#pragma unroll
  for (int ct = 0; ct < 16; ++ct) {
    __syncthreads();   // buf[ct%3] staged & visible
    const int cur = ct % 3, nxt = (ct + 1) % 3;

    // (a) LDS-write tile ct+1 (loaded 3 iters ago)
    if (ct < 15) {
      if (s_adj) *(i32x4*)&adj_lds[nxt][lofs] = sreg[nxt];
      else       *(i32x4*)&edge_lds[nxt][lofs] = sreg[nxt];
    }
    // (b) issue staging load for tile ct+4 (slot freed by (a))
    if (ct + 4 < 16) sreg[nxt] = *(const i32x4*)(sgp + TIDX(ct + 4) * 64);
    // (c) K/V register prefetch for iter ct+1
    if (ct < 15) {
      const int ti1 = TIDX(ct + 1);
#pragma unroll
      for (int t = 0; t < 4; ++t) {
        kf[(ct + 1) & 1][t] = *(const bf16x4*)(kbase + (size_t)(ti1 * 64 + t * 16) * 16);
        vf[(ct + 1) & 1][t] = *(const bf16x4*)(vbase + (size_t)ti1 * 1024 + t * 16);
      }
    }

    // (d) compute tile TIDX(ct): S^T = K.Q^T (pre-shifted), exp2, PV
    f32x4 st[4];
#pragma unroll
    for (int t = 0; t < 4; ++t) st[t] = mfma16(kf[ct & 1][t], qf, cinit);

#pragma unroll
    for (int t = 0; t < 4; ++t) {
      const i32x4 a4 = *(const i32x4*)&adj_lds[cur][lm * STI + t * 16 + g * 4];
      const i32x4 e4i = *(const i32x4*)&edge_lds[cur][lm * STI + t * 16 + g * 4];
      const f32x4 e4 = *(const f32x4*)&e4i;
      bf16x4 pf4;
#pragma unroll
      for (int j = 0; j < 4; ++j) {
        float p = __builtin_amdgcn_exp2f(fmaf(e4[j], Weh, st[t][j]));
        p = (a4[j] == 0) ? 0.f : p;
        lsum += p;
        pf4[j] = (short)f2bfu(p);
      }
      // P^T (S^T C/D layout) == B-frag of PV; O^T[d=4g+r][m=lm]
      oacc = mfma16(vf[ct & 1][t], pf4, oacc);
    }
  }

  // row-sum across lane groups {lm, lm+16, lm+32, lm+48}
  lsum += __shfl_xor(lsum, 16, 64);
  lsum += __shfl_xor(lsum, 32, 64);
  const float inv = 1.0f / lsum;
  bf16x4 ov;
  ov[0] = (short)f2bfu(oacc[0] * inv);
  ov[1] = (short)f2bfu(oacc[1] * inv);
  ov[2] = (short)f2bfu(oacc[2] * inv);
  ov[3] = (short)f2bfu(oacc[3] * inv);
  *(bf16x4*)(AO + ((size_t)b * 1024 + m0 + lm) * 128 + h * 16 + g * 4) = ov;
#undef TIDX
}

// ---------------------------------------------------------------------------
// Output projection: AO (bf16) @ Wo + bo -> f32 out.
// ---------------------------------------------------------------------------
__global__ __launch_bounds__(256) void gemm_out(
    const ushort* __restrict__ A, const float* __restrict__ W,
    const float* __restrict__ bias, float* __restrict__ C) {
  const int tid = threadIdx.x;
  const int l = tid & 63, w = tid >> 6;
  const int lm = l & 15, g = l >> 4;
  const int tile = blockIdx.x * 4 + w;
  const int mt = tile >> 3, nt = tile & 7;
  const int row = mt * 16 + lm;
  const int col = nt * 16 + lm;

  f32x4 acc = {0.f, 0.f, 0.f, 0.f};
#pragma unroll
  for (int ks = 0; ks < 8; ++ks) {
    bf16x4 a = *(const bf16x4*)(A + (size_t)row * 128 + ks * 16 + g * 4);
    const float* wp = W + (size_t)(ks * 16 + g * 4) * 128 + col;
    bf16x4 bf;
    bf[0] = (short)f2bfu(wp[0]);   bf[1] = (short)f2bfu(wp[128]);
    bf[2] = (short)f2bfu(wp[256]); bf[3] = (short)f2bfu(wp[384]);
    acc = mfma16(a, bf, acc);
  }
  const float bv = bias[col];
#pragma unroll
  for (int r = 0; r < 4; ++r)
    C[(size_t)(mt * 16 + g * 4 + r) * 128 + col] = acc[r] + bv;
}

extern "C" void kernel_launch(void* const* d_in, const int* in_sizes, int n_in,
                              void* d_out, int out_size, void* d_ws, size_t ws_size,
                              hipStream_t stream) {
  const float* x   = (const float*)d_in[0];
  const int*   adj = (const int*)d_in[1];
  const float* ew  = (const float*)d_in[2];
  const float* Wq  = (const float*)d_in[3];
  const float* bq  = (const float*)d_in[4];
  const float* Wk  = (const float*)d_in[5];
  const float* bk  = (const float*)d_in[6];
  const float* Wv  = (const float*)d_in[7];
  const float* bv  = (const float*)d_in[8];
  const float* Wo  = (const float*)d_in[9];
  const float* bo  = (const float*)d_in[10];
  const float* We  = (const float*)d_in[11];
  // be (d_in[12]) dropped: softmax(x + c) == softmax(x)

  const size_t MN = (size_t)8 * 1024 * 128;  // 1M elements
  ushort* Qs = (ushort*)d_ws;
  ushort* Kt = Qs + MN;
  ushort* Vt = Kt + MN;
  ushort* AO = Vt + MN;

  gemm_in<0><<<1024, 256, 0, stream>>>(x, Wq, bq, Qs, 0.25f * LOG2E);
  gemm_in<1><<<1024, 256, 0, stream>>>(x, Wk, bk, Kt, 1.0f);
  gemm_in<2><<<1024, 256, 0, stream>>>(x, Wv, bv, Vt, 1.0f);
  attn_kernel<<<512, 512, 0, stream>>>(Qs, Kt, Vt, adj, ew, We, AO);
  gemm_out<<<1024, 256, 0, stream>>>(AO, Wo, bo, (float*)d_out);
}